// Round 1
// baseline (253.405 us; speedup 1.0000x reference)
//
#include <hip/hip_runtime.h>

// Linear attention ("Transformers are RNNs") for N=8, L=S=8192, H=8, D=Dv=32, fp32.
// out[n,l,h,v] = (sum_d fQ[l,d] * KV[d,v]) / (sum_d fQ[l,d]*Ksum[d] + eps)
// KV[d,v] = sum_s fK[s,d]*V[s,v]; Ksum[d] = sum_s fK[s,d]; f(x)=elu(x)+1.
// The /S on V and *S on out cancel exactly (power-of-2 scaling).

#define L_Q 8192
#define S_K 8192
#define N_HEAD 8
#define DIM 32
#define RS (N_HEAD * DIM)   // 256 floats between consecutive s (or l) rows
#define EPSV 1e-6f

#define NPAIR 64            // N*H
#define WSFLOATS (NPAIR * 1056)  // per pair: 1024 KV + 32 Ksum

__device__ __forceinline__ float fmap(float x) {
    return x > 0.0f ? x + 1.0f : __expf(x);
}

// ---------------------------------------------------------------------------
// Kernel A: per (n,h), KV[32][32] and Ksum[32], split over S into CHUNKS.
// block = 256 threads = 4 waves. Each lane owns an 8d x 8v register tile;
// the 16 (wave,group) combos each consume one distinct staged row -> no
// redundant FLOPs. Cross-group reduce via shfl butterfly, cross-wave via LDS,
// then atomics into ws.
// ---------------------------------------------------------------------------
#define CHUNKS 16
#define SROWS (S_K / CHUNKS)  // 512
#define SKP 36                // padded LDS row stride (16B-aligned, kills conflicts)

__global__ __launch_bounds__(256) void kv_kernel(const float* __restrict__ K,
                                                 const float* __restrict__ V,
                                                 float* __restrict__ ws)
{
    __shared__ float sK[32][SKP];
    __shared__ float sV[32][SKP];
    __shared__ float sred[4][64][16];
    __shared__ float sredk[4][32];

    const int pair = blockIdx.y;          // n*8 + h
    const int n = pair >> 3, h = pair & 7;
    const int t = threadIdx.x;
    const int w = t >> 6;                 // wave 0..3
    const int l = t & 63;                 // lane
    const int g = l >> 4;                 // group 0..3 (lane bits 4,5)
    const int i = l & 15;                 // in-group index
    const int db = i >> 2;                // d block: d in [db*8, db*8+8)
    const int vb = i & 3;                 // v block: v in [vb*8, vb*8+8)

    // staging role: threads 0..127 stage K (with feature map), 128..255 stage V
    const int isV = (t >= 128);
    const int st = t & 127;
    const int srow = st >> 3;             // 0..15
    const int scol = (st & 7) * 4;        // 0,4,...,28
    const float* __restrict__ src = isV ? V : K;
    float* sdst = isV ? &sV[0][0] : &sK[0][0];

    const size_t base = ((size_t)n * S_K + (size_t)blockIdx.x * SROWS) * RS
                      + (size_t)h * DIM;

    float acc[8][8];
    float ksum[8];
    #pragma unroll
    for (int a = 0; a < 8; ++a) {
        ksum[a] = 0.0f;
        #pragma unroll
        for (int b = 0; b < 8; ++b) acc[a][b] = 0.0f;
    }

    const int myrow = g * 4 + w;          // the staged row this (wave,group) eats

    for (int s0 = 0; s0 < SROWS; s0 += 32) {
        __syncthreads();
        // stage 32 rows of K and V (float4, coalesced; K gets the feature map)
        #pragma unroll
        for (int rr = 0; rr < 2; ++rr) {
            const int row = srow + rr * 16;
            float4 val = *(const float4*)(src + base + (size_t)(s0 + row) * RS + scol);
            if (!isV) {
                val.x = fmap(val.x); val.y = fmap(val.y);
                val.z = fmap(val.z); val.w = fmap(val.w);
            }
            *(float4*)(sdst + row * SKP + scol) = val;
        }
        __syncthreads();
        // compute: each lane does 2 rows x (8x8 outer-product tile)
        #pragma unroll
        for (int rr = 0; rr < 2; ++rr) {
            const int r = myrow + rr * 16;
            const float4 k0 = *(const float4*)&sK[r][db * 8];
            const float4 k1 = *(const float4*)&sK[r][db * 8 + 4];
            const float4 v0 = *(const float4*)&sV[r][vb * 8];
            const float4 v1 = *(const float4*)&sV[r][vb * 8 + 4];
            const float kk[8] = {k0.x,k0.y,k0.z,k0.w,k1.x,k1.y,k1.z,k1.w};
            const float vv[8] = {v0.x,v0.y,v0.z,v0.w,v1.x,v1.y,v1.z,v1.w};
            #pragma unroll
            for (int a = 0; a < 8; ++a) {
                ksum[a] += kk[a];
                #pragma unroll
                for (int b = 0; b < 8; ++b) acc[a][b] += kk[a] * vv[b];
            }
        }
    }

    // reduce over the 4 groups (lane bits 4,5) with a shfl butterfly
    #pragma unroll
    for (int a = 0; a < 8; ++a) {
        #pragma unroll
        for (int b = 0; b < 8; ++b) {
            acc[a][b] += __shfl_xor(acc[a][b], 16);
            acc[a][b] += __shfl_xor(acc[a][b], 32);
        }
        ksum[a] += __shfl_xor(ksum[a], 16);
        ksum[a] += __shfl_xor(ksum[a], 32);
    }
    __syncthreads();
    if (l < 16) {
        #pragma unroll
        for (int a = 0; a < 8; ++a)
            #pragma unroll
            for (int b = 0; b < 8; ++b)
                sred[w][a * 8 + b][i] = acc[a][b];   // [k][i] layout: conflict-free
        if (vb == 0) {
            #pragma unroll
            for (int a = 0; a < 8; ++a) sredk[w][db * 8 + a] = ksum[a];
        }
    }
    __syncthreads();
    // cross-wave sum + one atomic per KV element
    float* KVp = ws + pair * 1056;
    #pragma unroll
    for (int p = t; p < 1024; p += 256) {
        const int kIdx = p >> 4, iIdx = p & 15;
        const float v = sred[0][kIdx][iIdx] + sred[1][kIdx][iIdx]
                      + sred[2][kIdx][iIdx] + sred[3][kIdx][iIdx];
        const int d  = ((iIdx >> 2) << 3) + (kIdx >> 3);
        const int vv = ((iIdx & 3) << 3) + (kIdx & 7);
        unsafeAtomicAdd(&KVp[d * DIM + vv], v);
    }
    if (t < 32) {
        const float v = sredk[0][t] + sredk[1][t] + sredk[2][t] + sredk[3][t];
        unsafeAtomicAdd(&KVp[1024 + t], v);
    }
}

// ---------------------------------------------------------------------------
// Kernel B: out rows. Block = 256 threads = 4 waves, 256 l-rows per block.
// Q staged TRANSPOSED in LDS (pad 260 keeps float4 chunks 16B-aligned and
// read conflicts at 2-way == free); each lane computes a 4-row x 8-v tile.
// ---------------------------------------------------------------------------
#define TP 260
#define BROWS 256

__global__ __launch_bounds__(256) void out_kernel(const float* __restrict__ Q,
                                                  const float* __restrict__ ws,
                                                  float* __restrict__ out)
{
    __shared__ float sQt[DIM][TP];     // transposed Q tile: [d][row]
    __shared__ float sKV[DIM][DIM];
    __shared__ float sKs[DIM];

    const int pair = blockIdx.y;
    const int n = pair >> 3, h = pair & 7;
    const int t = threadIdx.x;
    const int w = t >> 6, l = t & 63;
    const int vb = l & 3;              // v in [vb*8, vb*8+8)
    const int rb = l >> 2;             // rows w*64 + rb*4 .. +3

    const float* wp = ws + pair * 1056;
    for (int p = t; p < 1024; p += 256) (&sKV[0][0])[p] = wp[p];
    if (t < DIM) sKs[t] = wp[1024 + t];

    const int lrow = t >> 5;           // 0..7
    const int lcol = t & 31;
    const size_t qbase = ((size_t)n * L_Q + (size_t)blockIdx.x * BROWS) * RS
                       + (size_t)h * DIM;

    // stage 256 rows, transposed, feature map applied (coalesced global reads)
    #pragma unroll
    for (int rr = 0; rr < BROWS / 8; ++rr) {
        const int row = lrow + rr * 8;
        sQt[lcol][row] = fmap(Q[qbase + (size_t)row * RS + lcol]);
    }
    __syncthreads();

    const int rowbase = w * 64 + rb * 4;
    float acc[4][8];
    float den[4] = {0.0f, 0.0f, 0.0f, 0.0f};
    #pragma unroll
    for (int j = 0; j < 4; ++j)
        #pragma unroll
        for (int b = 0; b < 8; ++b) acc[j][b] = 0.0f;

    #pragma unroll
    for (int d = 0; d < DIM; ++d) {
        const float4 q4 = *(const float4*)&sQt[d][rowbase];
        const float ksd = sKs[d];
        const float4 c0 = *(const float4*)&sKV[d][vb * 8];
        const float4 c1 = *(const float4*)&sKV[d][vb * 8 + 4];
        const float qq[4] = {q4.x, q4.y, q4.z, q4.w};
        const float cc[8] = {c0.x,c0.y,c0.z,c0.w,c1.x,c1.y,c1.z,c1.w};
        #pragma unroll
        for (int j = 0; j < 4; ++j) {
            den[j] += qq[j] * ksd;
            #pragma unroll
            for (int b = 0; b < 8; ++b) acc[j][b] += qq[j] * cc[b];
        }
    }

    #pragma unroll
    for (int j = 0; j < 4; ++j) {
        const float z = 1.0f / (den[j] + EPSV);
        const size_t ob = qbase + (size_t)(rowbase + j) * RS + vb * 8;
        float4 o0, o1;
        o0.x = acc[j][0] * z; o0.y = acc[j][1] * z;
        o0.z = acc[j][2] * z; o0.w = acc[j][3] * z;
        o1.x = acc[j][4] * z; o1.y = acc[j][5] * z;
        o1.z = acc[j][6] * z; o1.w = acc[j][7] * z;
        *(float4*)(out + ob) = o0;
        *(float4*)(out + ob + 4) = o1;
    }
}

extern "C" void kernel_launch(void* const* d_in, const int* in_sizes, int n_in,
                              void* d_out, int out_size, void* d_ws, size_t ws_size,
                              hipStream_t stream)
{
    const float* Q = (const float*)d_in[0];
    const float* K = (const float*)d_in[1];
    const float* V = (const float*)d_in[2];
    float* outp = (float*)d_out;
    float* ws = (float*)d_ws;

    // atomics accumulate into ws -> must zero it every launch (ws is re-poisoned)
    hipMemsetAsync(d_ws, 0, WSFLOATS * sizeof(float), stream);

    dim3 gA(CHUNKS, NPAIR);
    kv_kernel<<<gA, 256, 0, stream>>>(K, V, ws);

    dim3 gB(L_Q / BROWS, NPAIR);
    out_kernel<<<gB, 256, 0, stream>>>(Q, ws, outp);
}